// Round 3
// baseline (602.073 us; speedup 1.0000x reference)
//
#include <hip/hip_runtime.h>
#include <stdint.h>

#define B_    64
#define CIN   64
#define L_IN  16384
#define COUT  128
#define K_    7
#define LP    16390          // padded positions (words) per b
#define LOUT  8189
#define TOUT  8
#define XCHUNK 16            // l-chunks
#define PBLK  512            // pooled outputs per block
#define WBLK  1036           // A-words staged per block
#define NSLOT 1104           // padded LDS slots (max used 1098)

// ---------------- pack W: sign bits along Cin into uint64, [co][k] ----------------
__global__ __launch_bounds__(256) void pack_W(const float* __restrict__ W,
                                              uint64_t* __restrict__ Bp) {
    int idx = blockIdx.x * 256 + threadIdx.x;
    if (idx >= COUT * K_) return;
    int co = idx / K_, k = idx - co * K_;
    uint64_t acc = 0;
#pragma unroll
    for (int ci = 0; ci < CIN; ++ci) {
        uint32_t s = __float_as_uint(W[(size_t)co * CIN * K_ + ci * K_ + k]) >> 31;
        acc |= (uint64_t)s << ci;
    }
    Bp[idx] = acc;
}

// ---------------- fused: pack A span -> LDS, binary conv + pool + threshold ----------------
__global__ __launch_bounds__(256, 4) void fused_bconv(
    const float* __restrict__ I, const uint64_t* __restrict__ Bp,
    const float* __restrict__ tp_, const float* __restrict__ tm_,
    const float* __restrict__ ps_, const float* __restrict__ ms_,
    float* __restrict__ out)
{
    __shared__ uint64_t lds[NSLOT];
    const int x = blockIdx.x;          // l-chunk 0..15
    const int b = blockIdx.y;          // 0..63
    const int t = threadIdx.x;

    // ===== phase 1: pack this block's A-span into LDS =====
    // block stages padded-A words wg in [1024x, 1024x+1035], stored at slot wl + wl/16.
    // word wg: pad (all ones) if wg<3 or wg>=16387; else sign-pack of I[b, :, wg-3].
    const int colbase = (x << 10) - 4;       // col of q=... group g covers cols colbase+4g .. +3
#pragma unroll 1
    for (int i = 0; i < 2; ++i) {
        int g = t + (i << 8);
        if (g < 260) {
            int col0 = colbase + (g << 2);
            uint32_t l0 = 0, l1 = 0, l2 = 0, l3 = 0;
            uint32_t h0 = 0, h1 = 0, h2 = 0, h3 = 0;
            if ((unsigned)col0 <= (unsigned)(L_IN - 4)) {
                const uint32_t* Ib = (const uint32_t*)(I + (size_t)b * CIN * L_IN + col0);
#pragma unroll 8
                for (int ci = 0; ci < 32; ++ci) {
                    uint4 v = *(const uint4*)(Ib + (size_t)ci * L_IN);
                    l0 |= (v.x >> 31) << ci;
                    l1 |= (v.y >> 31) << ci;
                    l2 |= (v.z >> 31) << ci;
                    l3 |= (v.w >> 31) << ci;
                }
#pragma unroll 8
                for (int ci = 0; ci < 32; ++ci) {
                    uint4 v = *(const uint4*)(Ib + (size_t)(ci + 32) * L_IN);
                    h0 |= (v.x >> 31) << ci;
                    h1 |= (v.y >> 31) << ci;
                    h2 |= (v.z >> 31) << ci;
                    h3 |= (v.w >> 31) << ci;
                }
            }
            uint64_t w[4] = { ((uint64_t)h0 << 32) | l0, ((uint64_t)h1 << 32) | l1,
                              ((uint64_t)h2 << 32) | l2, ((uint64_t)h3 << 32) | l3 };
#pragma unroll
            for (int q = 0; q < 4; ++q) {
                int wl = (g << 2) - 1 + q;               // word covered: wg = col+3
                if ((unsigned)wl < (unsigned)WBLK) {
                    int wg = (x << 10) + wl;
                    uint64_t val = (wg < 3 || wg >= L_IN + 3) ? ~0ULL : w[q];
                    lds[wl + (wl >> 4)] = val;
                }
            }
        }
    }
    __syncthreads();

    // ===== phase 2: binary conv + maxpool(7,2) + threshold =====
    const int cs = __builtin_amdgcn_readfirstlane(t >> 6);  // wave-uniform co-slot 0..3
    const int lt = t & 63;
    const int out0 = x * PBLK + lt * TOUT;
    const uint64_t* awin = &lds[lt * 17];    // slot of word wl0 = 16*lt

    const bool tail = (out0 + TOUT > LOUT);

#pragma unroll 1
    for (int ci_ = 0; ci_ < 32; ++ci_) {
        const int co = cs * 32 + ci_;                       // wave-uniform
        const uint64_t* Bco = Bp + co * K_;
        const uint64_t w0 = Bco[0], w1 = Bco[1], w2 = Bco[2], w3 = Bco[3],
                       w4 = Bco[4], w5 = Bco[5], w6 = Bco[6];

        // window: 27 words, LDS slot = base + m + m/16 (imm offsets)
        uint64_t a[27];
#pragma unroll
        for (int m = 0; m < 27; ++m) a[m] = awin[m + (m >> 4)];

        int s[2 * TOUT + 5];
#pragma unroll
        for (int j = 0; j < 2 * TOUT + 5; ++j) {
            int acc;
            acc  = __popcll(a[j + 0] ^ w0);
            acc += __popcll(a[j + 1] ^ w1);
            acc += __popcll(a[j + 2] ^ w2);
            acc += __popcll(a[j + 3] ^ w3);
            acc += __popcll(a[j + 4] ^ w4);
            acc += __popcll(a[j + 5] ^ w5);
            acc += __popcll(a[j + 6] ^ w6);
            s[j] = acc;
        }

        int p[TOUT + 2];
#pragma unroll
        for (int i = 0; i < TOUT + 2; ++i) p[i] = min(s[2 * i], s[2 * i + 1]);

        // pooled = 448 - 2*smin; pooled > thr  <=>  smin < (448-thr)/2; pooled>=0 <=> smin<=224
        const float ftp = (448.0f - tp_[co]) * 0.5f;
        const float ftm = (448.0f - tm_[co]) * 0.5f;
        const float ps = ps_[co], ms = ms_[co];
        float* op = out + ((size_t)(b * COUT + co)) * LOUT + out0;

        float r[TOUT];
#pragma unroll
        for (int o = 0; o < TOUT; ++o) {
            int smin = min(min(p[o], p[o + 1]), min(p[o + 2], s[2 * o + 6]));
            float sf  = (float)smin;
            float pos = sf < ftp ? ps : -ps;
            float neg = sf < ftm ? ms : -ms;
            r[o] = (sf <= 224.0f) ? pos : neg;
        }
        if (!tail) {
#pragma unroll
            for (int o = 0; o < TOUT; ++o) op[o] = r[o];
        } else {
#pragma unroll
            for (int o = 0; o < TOUT; ++o)
                if (out0 + o < LOUT) op[o] = r[o];
        }
    }
}

extern "C" void kernel_launch(void* const* d_in, const int* in_sizes, int n_in,
                              void* d_out, int out_size, void* d_ws, size_t ws_size,
                              hipStream_t stream) {
    const float* I  = (const float*)d_in[0];
    const float* W  = (const float*)d_in[1];
    const float* tp = (const float*)d_in[2];
    const float* tm = (const float*)d_in[3];
    const float* ps = (const float*)d_in[4];
    const float* ms = (const float*)d_in[5];
    float* out = (float*)d_out;

    uint64_t* Bp = (uint64_t*)d_ws;

    hipLaunchKernelGGL(pack_W, dim3((COUT * K_ + 255) / 256), dim3(256), 0, stream, W, Bp);
    hipLaunchKernelGGL(fused_bconv, dim3(XCHUNK, B_), dim3(256), 0, stream,
                       I, Bp, tp, tm, ps, ms, out);
}

// Round 4
// 599.376 us; speedup vs baseline: 1.0045x; 1.0045x over previous
//
#include <hip/hip_runtime.h>
#include <stdint.h>

#define B_    64
#define CIN   64
#define L_IN  16384
#define COUT  128
#define K_    7
#define LOUT  8189
#define TOUT  8
#define XCHUNK 16            // l-chunks
#define PBLK  512            // pooled outputs per block
#define WBLK  1036           // A-words staged per block
#define NSLOT 1104           // padded LDS slots (max used 1098)

// ---------------- pack W: sign bits along Cin into uint64, [co][k] ----------------
__global__ __launch_bounds__(256) void pack_W(const float* __restrict__ W,
                                              uint64_t* __restrict__ Bp) {
    int idx = blockIdx.x * 256 + threadIdx.x;
    if (idx >= COUT * K_) return;
    int co = idx / K_, k = idx - co * K_;
    uint64_t acc = 0;
#pragma unroll
    for (int ci = 0; ci < CIN; ++ci) {
        uint32_t s = __float_as_uint(W[(size_t)co * CIN * K_ + ci * K_ + k]) >> 31;
        acc |= (uint64_t)s << ci;
    }
    Bp[idx] = acc;
}

// pack 4 consecutive columns (one group) of I[b] into padded-A LDS words
__device__ __forceinline__ void pack_group(const float* __restrict__ I,
                                           int b, int x, int g,
                                           uint64_t* __restrict__ lds) {
    int col0 = ((x << 10) - 4) + (g << 2);
    uint32_t l0 = 0, l1 = 0, l2 = 0, l3 = 0;
    uint32_t h0 = 0, h1 = 0, h2 = 0, h3 = 0;
    if ((unsigned)col0 <= (unsigned)(L_IN - 4)) {
        const uint32_t* Ib = (const uint32_t*)(I + (size_t)b * CIN * L_IN + col0);
#pragma unroll 8
        for (int ci = 0; ci < 32; ++ci) {
            uint4 v = *(const uint4*)(Ib + (size_t)ci * L_IN);
            l0 |= (v.x >> 31) << ci;
            l1 |= (v.y >> 31) << ci;
            l2 |= (v.z >> 31) << ci;
            l3 |= (v.w >> 31) << ci;
        }
#pragma unroll 8
        for (int ci = 0; ci < 32; ++ci) {
            uint4 v = *(const uint4*)(Ib + (size_t)(ci + 32) * L_IN);
            h0 |= (v.x >> 31) << ci;
            h1 |= (v.y >> 31) << ci;
            h2 |= (v.z >> 31) << ci;
            h3 |= (v.w >> 31) << ci;
        }
    }
    uint64_t w[4] = { ((uint64_t)h0 << 32) | l0, ((uint64_t)h1 << 32) | l1,
                      ((uint64_t)h2 << 32) | l2, ((uint64_t)h3 << 32) | l3 };
#pragma unroll
    for (int q = 0; q < 4; ++q) {
        int wl = (g << 2) - 1 + q;                 // word wl covers col wl-3 (global wg = x*1024+wl)
        if ((unsigned)wl < (unsigned)WBLK) {
            int wg = (x << 10) + wl;
            uint64_t val = (wg < 3 || wg >= L_IN + 3) ? ~0ULL : w[q];
            lds[wl + (wl >> 4)] = val;
        }
    }
}

// ---------------- fused: pack A span -> LDS, binary conv + pool + threshold ----------------
__global__ __launch_bounds__(256, 4) void fused_bconv(
    const float* __restrict__ I, const uint64_t* __restrict__ Bp,
    const float* __restrict__ tp_, const float* __restrict__ tm_,
    const float* __restrict__ ps_, const float* __restrict__ ms_,
    float* __restrict__ out)
{
    __shared__ uint64_t lds[NSLOT];
    const int x = blockIdx.x;          // l-chunk 0..15
    const int b = blockIdx.y;          // 0..63
    const int t = threadIdx.x;

    // ===== phase 1: pack this block's A-span into LDS =====
    pack_group(I, b, x, t, lds);
    if ((t & 63) == 63) pack_group(I, b, x, 256 + (t >> 6), lds);   // 4 tail groups, one per wave
    __syncthreads();

    // ===== phase 2: binary conv + maxpool(7,2) + threshold =====
    const int cs = __builtin_amdgcn_readfirstlane(t >> 6);  // wave-uniform co-slot 0..3
    const int lt = t & 63;
    int out0 = x * PBLK + lt * TOUT;
    if (out0 > LOUT - TOUT) out0 = LOUT - TOUT;             // clamp: duplicate lanes write same values

    // load this thread's 27-word window ONCE, then pin into VGPRs (no remat possible)
    const int wl0 = 2 * out0 - (x << 10);
    uint64_t a[27];
#pragma unroll
    for (int m = 0; m < 27; ++m) {
        int wl = wl0 + m;
        a[m] = lds[wl + (wl >> 4)];
    }
#pragma unroll
    for (int m = 0; m < 27; ++m) asm("" : "+v"(a[m]));

#pragma unroll 1
    for (int ci_ = 0; ci_ < 32; ++ci_) {
        const int co = cs * 32 + ci_;                       // wave-uniform
        const uint64_t* Bco = Bp + co * K_;
        const uint64_t w0 = Bco[0], w1 = Bco[1], w2 = Bco[2], w3 = Bco[3],
                       w4 = Bco[4], w5 = Bco[5], w6 = Bco[6];

        int s[2 * TOUT + 5];
#pragma unroll
        for (int j = 0; j < 2 * TOUT + 5; ++j) {
            int acc;
            acc  = __popcll(a[j + 0] ^ w0);
            acc += __popcll(a[j + 1] ^ w1);
            acc += __popcll(a[j + 2] ^ w2);
            acc += __popcll(a[j + 3] ^ w3);
            acc += __popcll(a[j + 4] ^ w4);
            acc += __popcll(a[j + 5] ^ w5);
            acc += __popcll(a[j + 6] ^ w6);
            s[j] = acc;
        }

        int p[TOUT + 2];
#pragma unroll
        for (int i = 0; i < TOUT + 2; ++i) p[i] = min(s[2 * i], s[2 * i + 1]);

        // pooled = 448 - 2*smin; pooled > thr <=> smin < (448-thr)/2; pooled >= 0 <=> smin <= 224
        const float ftp = (448.0f - tp_[co]) * 0.5f;
        const float ftm = (448.0f - tm_[co]) * 0.5f;
        const float ps = ps_[co], ms = ms_[co];
        float* op = out + ((size_t)(b * COUT + co)) * LOUT + out0;
#pragma unroll
        for (int o = 0; o < TOUT; ++o) {
            int smin = min(min(p[o], p[o + 1]), min(p[o + 2], s[2 * o + 6]));
            float sf  = (float)smin;
            float pos = sf < ftp ? ps : -ps;
            float neg = sf < ftm ? ms : -ms;
            op[o] = (sf <= 224.0f) ? pos : neg;
        }
    }
}

extern "C" void kernel_launch(void* const* d_in, const int* in_sizes, int n_in,
                              void* d_out, int out_size, void* d_ws, size_t ws_size,
                              hipStream_t stream) {
    const float* I  = (const float*)d_in[0];
    const float* W  = (const float*)d_in[1];
    const float* tp = (const float*)d_in[2];
    const float* tm = (const float*)d_in[3];
    const float* ps = (const float*)d_in[4];
    const float* ms = (const float*)d_in[5];
    float* out = (float*)d_out;

    uint64_t* Bp = (uint64_t*)d_ws;

    hipLaunchKernelGGL(pack_W, dim3((COUT * K_ + 255) / 256), dim3(256), 0, stream, W, Bp);
    hipLaunchKernelGGL(fused_bconv, dim3(XCHUNK, B_), dim3(256), 0, stream,
                       I, Bp, tp, tm, ps, ms, out);
}